// Round 2
// baseline (764.208 us; speedup 1.0000x reference)
//
#include <hip/hip_runtime.h>

// Problem constants: N=1e6 rows, D_IN=128, D_OUT=64, C=64.
#define C_CLASSES 64
#define D_IN 128
#define D_OUT 64
#define CHUNK 32                    // rows per K-chunk (one 16x16x32 K-step)
#define CHUNK_FLTS (CHUNK * D_IN)   // 4096 floats = 16 KB
#define GSUM_FLTS (C_CLASSES * D_IN) // 8192
#define NBLK 1024                   // seg_mm grid (4 blocks/CU, LDS 32KB each)

// protos = (seg_sum(X)@W + cnt*b)/max(cnt,1); seg_sum(X) = OneHot(labels)^T @ X
//
// R5 analysis: timed region = ~630us of harness 2GB workspace-poison fills
// (two ~315us fillBufferAligned per iteration, 6.4 TB/s — untouchable) plus
// ~85us of our kernels. Our floor: 512MB X read = 81us. This round reclaims
// the controllable slack:
//  (1) partials+reduce (R4) reverted to atomic epilogue — the R3-vs-R4 A/B
//      showed the 64MB partials round-trip cost ~8us net vs 8.4M L2-resident
//      atomics.
//  (2) count_kernel 256->1024 blocks (was 4 waves/CU, latency-exposed).
//  (3) B-frag LDS reads were 4-way bank-conflicted (bank = (u*16+n16)%32,
//      same for all quads). XOR column-bit-4 with (k>>3)&1: quads split
//      across bank halves -> 2-way aliasing = free (m136). Swizzle applied
//      both-sides (rule #21): pre-swizzled per-lane GLOBAL source offsets
//      feed the linear global_load_lds dest; read side swaps u for odd quads.

typedef __attribute__((ext_vector_type(8))) __bf16 bf16x8;
typedef __attribute__((ext_vector_type(8))) unsigned short us8;
typedef __attribute__((ext_vector_type(4))) float f32x4;

union frag_cast { us8 u; bf16x8 b; };

// float -> bf16 round-to-nearest-even.
__device__ __forceinline__ unsigned short f2bf(float f) {
    unsigned u = __float_as_uint(f);
    unsigned r = u + 0x7FFFu + ((u >> 16) & 1u);
    return (unsigned short)(r >> 16);
}

// Async global->LDS, 16B per lane. LDS dest = wave-uniform base + lane*16.
__device__ __forceinline__ void stage16(const float* g, float* l) {
    __builtin_amdgcn_global_load_lds(
        (const __attribute__((address_space(1))) unsigned int*)g,
        (__attribute__((address_space(3))) unsigned int*)l, 16, 0, 0);
}

// --- Kernel 1: S = OneHot^T @ X via mfma_f32_16x16x32_bf16, LDS-staged -----
// Block = 256 thr = 4 waves; block covers full 64x128 output. Wave w owns
// cols [32w,32w+32): 4 class-tiles x 2 col-tiles = 8 acc frags.
// Layouts (R2-verified): A[m][k] m=lane&15,k=quad*8+j; B[k][n] n=lane&15;
// D[m][n] m=quad*4+r, n=lane&15.
//
// LDS swizzle: logical element (k, d) lives at float offset
//   k*128 + (d ^ (((k>>3)&1) << 4)).
// Write side: global_load_lds dest stays LINEAR; each lane's 16B global
// source offset is pre-permuted (the 4-float granule sits inside one
// 8-aligned block, and the XOR is a multiple of 16 floats, so the 16B
// source stays contiguous). Read side: column bit 4 is exactly u, so the
// swizzle is just u -> u ^ (quad&1).
//
// Sync: raw s_barrier + counted vmcnt(6) (next chunk's 4 DMA + 2 label
// loads stay in flight across the whole iteration; vmcnt retires in order).
__global__ __launch_bounds__(256) void seg_mm_kernel(
    const float* __restrict__ x, const int* __restrict__ labels,
    float* __restrict__ gsum, int n)
{
    __shared__ float buf[2][CHUNK_FLTS];   // 2 x 16 KB double buffer

    const int lane = threadIdx.x & 63;
    const int wave = threadIdx.x >> 6;     // 0..3
    const int n16  = lane & 15;
    const int quad = lane >> 4;            // 0..3
    const int cb   = wave * 32;            // wave's column base
    const int xu   = quad & 1;             // read-side swizzle bit

    f32x4 acc[4][2];
#pragma unroll
    for (int t = 0; t < 4; ++t)
#pragma unroll
        for (int u = 0; u < 2; ++u)
            acc[t][u] = (f32x4){0.f, 0.f, 0.f, 0.f};

    const int stride = (int)gridDim.x * CHUNK;
    const int rb0    = (int)blockIdx.x * CHUNK;
    const int lslice = wave * 256;         // wave-uniform LDS float offset

    // Pre-swizzled per-lane global source offsets (floats within a chunk).
    int goff[4];
#pragma unroll
    for (int r = 0; r < 4; ++r) {
        const int o = r * 1024 + lslice + lane * 4;  // linear chunk offset
        const int k = o >> 7;                         // row within chunk
        const int d = o & 127;                        // col
        goff[r] = k * D_IN + (d ^ (((k >> 3) & 1) << 4));
    }

    // Prologue: stage chunk 0 (4 DMA ops) then its labels (2 dwordx4 loads).
    int4 pl0 = {0,0,0,0}, pl1 = {0,0,0,0};
    if (rb0 < n) {
#pragma unroll
        for (int r = 0; r < 4; ++r)
            stage16(x + (size_t)rb0 * D_IN + goff[r],
                    &buf[0][r * 1024 + lslice]);
        pl0 = *(const int4*)(labels + rb0 + quad * 8);
        pl1 = *(const int4*)(labels + rb0 + quad * 8 + 4);
    }

    int bufi = 0;
    for (int rb = rb0; rb < n; rb += stride, bufi ^= 1) {
        const int rbn = rb + stride;
        const bool hasNext = rbn < n;      // block-uniform
        int4 pn0, pn1;
        if (hasNext) {                     // issue next chunk: 4 DMA + 2 loads
#pragma unroll
            for (int r = 0; r < 4; ++r)
                stage16(x + (size_t)rbn * D_IN + goff[r],
                        &buf[bufi ^ 1][r * 1024 + lslice]);
            pn0 = *(const int4*)(labels + rbn + quad * 8);
            pn1 = *(const int4*)(labels + rbn + quad * 8 + 4);
        }

        // Counted wait: 6 younger vmem ops (next chunk) stay in flight.
        if (hasNext) {
            asm volatile("s_waitcnt vmcnt(6)\n\ts_barrier" ::: "memory");
        } else {
            asm volatile("s_waitcnt vmcnt(0)\n\ts_barrier" ::: "memory");
        }

        const int labv[8] = {pl0.x, pl0.y, pl0.z, pl0.w,
                             pl1.x, pl1.y, pl1.z, pl1.w};

        // B frags from LDS (swizzled): buf[k*128 + cb + ((u^xu)*16) + n16],
        // k = quad*8+j. Per instruction, quads split across bank halves.
        const float* lb = &buf[bufi][(quad * 8) * D_IN + cb + n16];
        frag_cast bfrag[2];
#pragma unroll
        for (int u = 0; u < 2; ++u)
#pragma unroll
            for (int j = 0; j < 8; ++j)
                bfrag[u].u[j] = f2bf(lb[j * D_IN + ((u ^ xu) * 16)]);

        // A frags: one-hot from prefetched labels.
        frag_cast afrag[4];
#pragma unroll
        for (int t = 0; t < 4; ++t)
#pragma unroll
            for (int j = 0; j < 8; ++j)
                afrag[t].u[j] = (labv[j] == t * 16 + n16)
                                    ? (unsigned short)0x3F80u : (unsigned short)0u;

#pragma unroll
        for (int t = 0; t < 4; ++t)
#pragma unroll
            for (int u = 0; u < 2; ++u)
                acc[t][u] = __builtin_amdgcn_mfma_f32_16x16x32_bf16(
                    afrag[t].b, bfrag[u].b, acc[t][u], 0, 0, 0);

        // All waves done reading buf[bufi] before iter i+1 overwrites it.
        asm volatile("s_barrier" ::: "memory");

        if (hasNext) { pl0 = pn0; pl1 = pn1; }
    }

    // Epilogue: D[class = 16t + quad*4 + r][col = cb + 16u + n16].
    // 8192 atomics/block onto the 32KB L2-resident gsum.
#pragma unroll
    for (int t = 0; t < 4; ++t)
#pragma unroll
        for (int u = 0; u < 2; ++u)
#pragma unroll
            for (int r = 0; r < 4; ++r)
                unsafeAtomicAdd(
                    &gsum[(t * 16 + quad * 4 + r) * D_IN + cb + u * 16 + n16],
                    acc[t][u][r]);
}

// --- Kernel 2: class counts via wave ballot --------------------------------
__global__ __launch_bounds__(256) void count_kernel(
    const int* __restrict__ labels, float* __restrict__ gcnt, int n)
{
    const int lane = threadIdx.x & 63;
    const int gw   = (int)(blockIdx.x * blockDim.x + threadIdx.x) >> 6;
    const int nw   = (int)(gridDim.x * blockDim.x) >> 6;

    int cnt = 0;
    for (int base = gw * 64; base < n; base += nw * 64) {  // n % 64 == 0
        const int lab = labels[base + lane];
#pragma unroll
        for (int c = 0; c < C_CLASSES; ++c) {
            unsigned long long m = __ballot(lab == c);
            cnt += (lane == c) ? __popcll(m) : 0;
        }
    }
    unsafeAtomicAdd(&gcnt[lane], (float)cnt);  // lane == class
}

// --- Kernel 3: tiny GEMM + bias + normalize --------------------------------
__global__ __launch_bounds__(256) void proto_kernel(
    const float* __restrict__ gsum, const float* __restrict__ gcnt,
    const float* __restrict__ W, const float* __restrict__ b,
    float* __restrict__ out)
{
    const int t = (int)(blockIdx.x * blockDim.x + threadIdx.x);
    const int c = t >> 6;
    const int e = t & 63;

    const float* srow = gsum + (c << 7);
    float acc = 0.0f;
#pragma unroll
    for (int k = 0; k < D_IN; ++k)
        acc = fmaf(srow[k], W[k * D_OUT + e], acc);

    const float cnt = gcnt[c];
    out[(c << 6) + e] = (acc + cnt * b[e]) / fmaxf(cnt, 1.0f);
}

extern "C" void kernel_launch(void* const* d_in, const int* in_sizes, int n_in,
                              void* d_out, int out_size, void* d_ws, size_t ws_size,
                              hipStream_t stream)
{
    const float* x      = (const float*)d_in[0];
    const int*   labels = (const int*)d_in[1];
    const float* W      = (const float*)d_in[2];
    const float* b      = (const float*)d_in[3];
    float*       out    = (float*)d_out;

    float* gsum = (float*)d_ws;                  // [64*128]
    float* gcnt = gsum + GSUM_FLTS;              // [64]

    const int n = in_sizes[0] / D_IN;            // 1,000,000 (multiple of 64)

    hipMemsetAsync(d_ws, 0, (GSUM_FLTS + C_CLASSES) * sizeof(float), stream);

    // 1024 blocks x 4 waves, 32 KB LDS each -> 4 blocks/CU, 16 waves/CU.
    seg_mm_kernel<<<NBLK, 256, 0, stream>>>(x, labels, gsum, n);

    count_kernel<<<1024, 256, 0, stream>>>(labels, gcnt, n);

    proto_kernel<<<(C_CLASSES * D_OUT) / 256, 256, 0, stream>>>(gsum, gcnt, W, b, out);
}

// Round 3
// 683.120 us; speedup vs baseline: 1.1187x; 1.1187x over previous
//
#include <hip/hip_runtime.h>

// Problem constants: N=1e6 rows, D_IN=128, D_OUT=64, C=64.
#define C_CLASSES 64
#define D_IN 128
#define D_OUT 64
#define CHUNK 32                    // rows per K-chunk (one 16x16x32 K-step)
#define CHUNK_FLTS (CHUNK * D_IN)   // 4096 floats = 16 KB
#define GSUM_FLTS (C_CLASSES * D_IN) // 8192
#define NBLK 1024                   // seg_mm grid (4 blocks/CU, LDS 32KB each)

// protos = (seg_sum(X)@W + cnt*b)/max(cnt,1); seg_sum(X) = OneHot(labels)^T @ X
//
// R6. Within-session A/B (R1 partials 715.6 vs R2 atomics 764.2) shows the
// atomic epilogue costs ~49us (8.4M scalar f32 atomics, 1024-way/address
// TCC serialization + 32K VMEM issue slots/CU). Restore partials, improved:
//  (1) TRANSPOSED partials [blk][col*64+class]: acc's r-index = 4 consecutive
//      classes -> each acc[t][u] is ONE dwordx4 store (8 vec stores/thread
//      vs 32 scalars in R4).
//  (2) counts fused into seg_mm: counts = OneHot^T @ ones = 4 extra MFMAs
//      per chunk with an all-ones B frag. count_kernel deleted.
//  (3) reduce kernel is atomic-free (block-owned slots + LDS fold, plain
//      stores) -> no gsum pre-zero -> hipMemsetAsync deleted. 5->3 launches.
//  (4) keep R5's LDS swizzle (4-way -> free 2-way) and counted vmcnt(6).

typedef __attribute__((ext_vector_type(8))) __bf16 bf16x8;
typedef __attribute__((ext_vector_type(8))) unsigned short us8;
typedef __attribute__((ext_vector_type(4))) float f32x4;

union frag_cast { us8 u; bf16x8 b; };

// float -> bf16 round-to-nearest-even.
__device__ __forceinline__ unsigned short f2bf(float f) {
    unsigned u = __float_as_uint(f);
    unsigned r = u + 0x7FFFu + ((u >> 16) & 1u);
    return (unsigned short)(r >> 16);
}

// Async global->LDS, 16B per lane. LDS dest = wave-uniform base + lane*16.
__device__ __forceinline__ void stage16(const float* g, float* l) {
    __builtin_amdgcn_global_load_lds(
        (const __attribute__((address_space(1))) unsigned int*)g,
        (__attribute__((address_space(3))) unsigned int*)l, 16, 0, 0);
}

// --- Kernel 1: S = OneHot^T @ X via mfma_f32_16x16x32_bf16, LDS-staged -----
// Block = 256 thr = 4 waves; block covers full 64x128 output. Wave w owns
// cols [32w,32w+32): 4 class-tiles x 2 col-tiles = 8 acc frags.
// Layouts (R2-verified): A[m][k] m=lane&15,k=quad*8+j; B[k][n] n=lane&15;
// D[m][n] m=quad*4+r, n=lane&15.
//
// LDS swizzle (R5-verified): element (k,d) at float offset
// k*128 + (d ^ (((k>>3)&1)<<4)); write side via pre-swizzled global source
// offsets into a LINEAR global_load_lds dest; read side: u -> u ^ (quad&1).
//
// Sync: raw s_barrier + counted vmcnt(6): next chunk's 4 DMA + 2 label
// loads stay in flight across the whole iteration (vmcnt retires in order).
__global__ __launch_bounds__(256) void seg_mm_kernel(
    const float* __restrict__ x, const int* __restrict__ labels,
    float* __restrict__ partials, float* __restrict__ cnt_p, int n)
{
    __shared__ float buf[2][CHUNK_FLTS];   // 2 x 16 KB double buffer

    const int lane = threadIdx.x & 63;
    const int wave = threadIdx.x >> 6;     // 0..3
    const int n16  = lane & 15;
    const int quad = lane >> 4;            // 0..3
    const int cb   = wave * 32;            // wave's column base
    const int xu   = quad & 1;             // read-side swizzle bit

    f32x4 acc[4][2];
    f32x4 acc_cnt[4];
#pragma unroll
    for (int t = 0; t < 4; ++t) {
        acc_cnt[t] = (f32x4){0.f, 0.f, 0.f, 0.f};
#pragma unroll
        for (int u = 0; u < 2; ++u)
            acc[t][u] = (f32x4){0.f, 0.f, 0.f, 0.f};
    }

    // All-ones B fragment (bf16 1.0 = 0x3F80) for the count MFMA.
    frag_cast ones;
#pragma unroll
    for (int j = 0; j < 8; ++j) ones.u[j] = (unsigned short)0x3F80u;

    const int stride = (int)gridDim.x * CHUNK;
    const int rb0    = (int)blockIdx.x * CHUNK;
    const int lslice = wave * 256;         // wave-uniform LDS float offset

    // Pre-swizzled per-lane global source offsets (floats within a chunk).
    int goff[4];
#pragma unroll
    for (int r = 0; r < 4; ++r) {
        const int o = r * 1024 + lslice + lane * 4;  // linear chunk offset
        const int k = o >> 7;                         // row within chunk
        const int d = o & 127;                        // col
        goff[r] = k * D_IN + (d ^ (((k >> 3) & 1) << 4));
    }

    // Prologue: stage chunk 0 (4 DMA ops) then its labels (2 dwordx4 loads).
#pragma unroll
    for (int r = 0; r < 4; ++r)
        stage16(x + (size_t)rb0 * D_IN + goff[r],
                &buf[0][r * 1024 + lslice]);
    int4 pl0 = *(const int4*)(labels + rb0 + quad * 8);
    int4 pl1 = *(const int4*)(labels + rb0 + quad * 8 + 4);

    int bufi = 0;
    for (int rb = rb0; rb < n; rb += stride, bufi ^= 1) {
        const int rbn = rb + stride;
        const bool hasNext = rbn < n;      // block-uniform
        int4 pn0, pn1;
        if (hasNext) {                     // issue next chunk: 4 DMA + 2 loads
#pragma unroll
            for (int r = 0; r < 4; ++r)
                stage16(x + (size_t)rbn * D_IN + goff[r],
                        &buf[bufi ^ 1][r * 1024 + lslice]);
            pn0 = *(const int4*)(labels + rbn + quad * 8);
            pn1 = *(const int4*)(labels + rbn + quad * 8 + 4);
        }

        // Counted wait: 6 younger vmem ops (next chunk) stay in flight.
        if (hasNext) {
            asm volatile("s_waitcnt vmcnt(6)\n\ts_barrier" ::: "memory");
        } else {
            asm volatile("s_waitcnt vmcnt(0)\n\ts_barrier" ::: "memory");
        }

        const int labv[8] = {pl0.x, pl0.y, pl0.z, pl0.w,
                             pl1.x, pl1.y, pl1.z, pl1.w};

        // B frags from LDS (swizzled): buf[k*128 + cb + ((u^xu)*16) + n16],
        // k = quad*8+j. Per instruction, quads split across bank halves.
        const float* lb = &buf[bufi][(quad * 8) * D_IN + cb + n16];
        frag_cast bfrag[2];
#pragma unroll
        for (int u = 0; u < 2; ++u)
#pragma unroll
            for (int j = 0; j < 8; ++j)
                bfrag[u].u[j] = f2bf(lb[j * D_IN + ((u ^ xu) * 16)]);

        // A frags: one-hot from prefetched labels.
        frag_cast afrag[4];
#pragma unroll
        for (int t = 0; t < 4; ++t)
#pragma unroll
            for (int j = 0; j < 8; ++j)
                afrag[t].u[j] = (labv[j] == t * 16 + n16)
                                    ? (unsigned short)0x3F80u : (unsigned short)0u;

#pragma unroll
        for (int t = 0; t < 4; ++t) {
#pragma unroll
            for (int u = 0; u < 2; ++u)
                acc[t][u] = __builtin_amdgcn_mfma_f32_16x16x32_bf16(
                    afrag[t].b, bfrag[u].b, acc[t][u], 0, 0, 0);
            // counts: D[m][n] = sum_k onehot[m][k] * 1 = count(class m)
            acc_cnt[t] = __builtin_amdgcn_mfma_f32_16x16x32_bf16(
                afrag[t].b, ones.b, acc_cnt[t], 0, 0, 0);
        }

        // All waves done reading buf[bufi] before iter i+1 overwrites it.
        asm volatile("s_barrier" ::: "memory");

        if (hasNext) { pl0 = pn0; pl1 = pn1; }
    }

    // Epilogue (transposed partials): slot = col*64 + class;
    // class = 16t + quad*4 + r  ->  r is contiguous -> dwordx4 stores.
    float* pT = partials + (size_t)blockIdx.x * GSUM_FLTS;
#pragma unroll
    for (int t = 0; t < 4; ++t)
#pragma unroll
        for (int u = 0; u < 2; ++u) {
            const int col = cb + u * 16 + n16;
            *(f32x4*)&pT[col * C_CLASSES + t * 16 + quad * 4] = acc[t][u];
        }

    // Per-block counts (all waves computed identical acc_cnt; wave 0,
    // column-0 lanes write): cnt_p[blk][class].
    if (wave == 0 && n16 == 0) {
        float* cp = cnt_p + (size_t)blockIdx.x * C_CLASSES;
#pragma unroll
        for (int t = 0; t < 4; ++t)
            *(f32x4*)&cp[t * 16 + quad * 4] = acc_cnt[t];
    }
}

// --- Kernel 1b: atomic-free reduction ---------------------------------------
// Blocks 0..255: slot s = b*32 + (t&31); 8 threads/slot sum 128 partials
// each, LDS fold, plain store to gsumT[s]. Block 256: counts (4 thr/class).
__global__ __launch_bounds__(256) void reduce_kernel(
    const float* __restrict__ partials, const float* __restrict__ cnt_p,
    float* __restrict__ gsumT, float* __restrict__ gcnt)
{
    __shared__ float red[256];
    const int b = (int)blockIdx.x;
    const int t = (int)threadIdx.x;

    if (b < 256) {
        const int s   = b * 32 + (t & 31);
        const int oct = t >> 5;                     // 0..7
        float a = 0.f;
#pragma unroll 8
        for (int p = oct * 128; p < oct * 128 + 128; ++p)
            a += partials[(size_t)p * GSUM_FLTS + s];
        red[t] = a;
        __syncthreads();
        if (oct == 0) {
            float v = 0.f;
#pragma unroll
            for (int o = 0; o < 8; ++o) v += red[o * 32 + t];
            gsumT[s] = v;
        }
    } else {
        const int c = t & 63;
        const int q = t >> 6;                       // 0..3
        float a = 0.f;
#pragma unroll 8
        for (int p = q * 256; p < q * 256 + 256; ++p)
            a += cnt_p[(size_t)p * C_CLASSES + c];
        red[t] = a;
        __syncthreads();
        if (q == 0)
            gcnt[c] = red[c] + red[64 + c] + red[128 + c] + red[192 + c];
    }
}

// --- Kernel 3: tiny GEMM + bias + normalize --------------------------------
// gsumT layout: gsumT[k*64 + c] = seg_sum[c][k]. Per wave, all lanes share c
// -> gsumT reads are broadcasts; W reads are coalesced.
__global__ __launch_bounds__(256) void proto_kernel(
    const float* __restrict__ gsumT, const float* __restrict__ gcnt,
    const float* __restrict__ W, const float* __restrict__ b,
    float* __restrict__ out)
{
    const int t = (int)(blockIdx.x * blockDim.x + threadIdx.x);
    const int c = t >> 6;
    const int e = t & 63;

    float acc = 0.0f;
#pragma unroll
    for (int k = 0; k < D_IN; ++k)
        acc = fmaf(gsumT[k * C_CLASSES + c], W[k * D_OUT + e], acc);

    const float cnt = gcnt[c];
    out[(c << 6) + e] = (acc + cnt * b[e]) / fmaxf(cnt, 1.0f);
}

extern "C" void kernel_launch(void* const* d_in, const int* in_sizes, int n_in,
                              void* d_out, int out_size, void* d_ws, size_t ws_size,
                              hipStream_t stream)
{
    const float* x      = (const float*)d_in[0];
    const int*   labels = (const int*)d_in[1];
    const float* W      = (const float*)d_in[2];
    const float* b      = (const float*)d_in[3];
    float*       out    = (float*)d_out;

    float* gsumT    = (float*)d_ws;                    // [8192] transposed
    float* gcnt     = gsumT + GSUM_FLTS;               // [64]
    float* partials = gcnt + C_CLASSES;                // [NBLK][8192]
    float* cnt_p    = partials + (size_t)NBLK * GSUM_FLTS; // [NBLK][64]

    const int n = in_sizes[0] / D_IN;                  // 1,000,000

    // ~33.9 MB; observed ws is ~2 GB (WRITE_SIZE of the poison fills).
    // No memset needed: every workspace slot we read is written first.

    // 1024 blocks x 4 waves, 32 KB LDS each -> 4 blocks/CU, 16 waves/CU.
    seg_mm_kernel<<<NBLK, 256, 0, stream>>>(x, labels, partials, cnt_p, n);

    reduce_kernel<<<257, 256, 0, stream>>>(partials, cnt_p, gsumT, gcnt);

    proto_kernel<<<(C_CLASSES * D_OUT) / 256, 256, 0, stream>>>(
        gsumT, gcnt, W, b, out);
}